// Round 1
// baseline (534.315 us; speedup 1.0000x reference)
//
#include <hip/hip_runtime.h>
#include <math.h>

#define T_TOK 16384
#define DIM   2048
#define NE    64
#define NACT  8
#define ALPHA 1e-4f
#define EPSV  1e-9f

// ---------------------------------------------------------------------------
// Kernel 1: affinity = sigmoid(x @ W^T), fp64 accumulation for exactness.
// Grid: 256 blocks, 256 threads. Block tile: 64 tokens x 64 experts, BK=32.
// LDS dd-major [32][68]: pad 68 -> compute reads are 2-way bank-aliased (free),
// rows are 272B (16B multiple) so float4 LDS reads stay b128.
// ---------------------------------------------------------------------------
__global__ __launch_bounds__(256) void gemm_aff(const float* __restrict__ x,
                                                const float* __restrict__ Wg,
                                                float* __restrict__ A) {
    __shared__ __align__(16) float xs[32][68];
    __shared__ __align__(16) float wsm[32][68];

    const int tid = threadIdx.x;
    const int tokBase = blockIdx.x * 64;
    const int tg = tid & 15;   // token group: tokens tg*4 .. tg*4+3
    const int eg = tid >> 4;   // expert group: experts eg*4 .. eg*4+3

    double acc[4][4];
#pragma unroll
    for (int i = 0; i < 4; ++i)
#pragma unroll
        for (int j = 0; j < 4; ++j) acc[i][j] = 0.0;

    for (int d0 = 0; d0 < DIM; d0 += 32) {
#pragma unroll
        for (int q = 0; q < 2; ++q) {
            const int f   = tid + q * 256;     // 0..511
            const int row = f >> 3;            // 0..63
            const int dd  = (f & 7) * 4;       // 0,4,...,28
            const float4 xv = *(const float4*)(x + (size_t)(tokBase + row) * DIM + d0 + dd);
            xs[dd + 0][row] = xv.x;
            xs[dd + 1][row] = xv.y;
            xs[dd + 2][row] = xv.z;
            xs[dd + 3][row] = xv.w;
            const float4 wv = *(const float4*)(Wg + (size_t)row * DIM + d0 + dd);
            wsm[dd + 0][row] = wv.x;
            wsm[dd + 1][row] = wv.y;
            wsm[dd + 2][row] = wv.z;
            wsm[dd + 3][row] = wv.w;
        }
        __syncthreads();

#pragma unroll
        for (int dd = 0; dd < 32; ++dd) {
            const float4 xa = *(const float4*)&xs[dd][tg * 4];
            const float4 wa = *(const float4*)&wsm[dd][eg * 4];
            const double xd[4] = {(double)xa.x, (double)xa.y, (double)xa.z, (double)xa.w};
            const double wd[4] = {(double)wa.x, (double)wa.y, (double)wa.z, (double)wa.w};
#pragma unroll
            for (int i = 0; i < 4; ++i)
#pragma unroll
                for (int j = 0; j < 4; ++j) acc[i][j] = fma(xd[i], wd[j], acc[i][j]);
        }
        __syncthreads();
    }

#pragma unroll
    for (int i = 0; i < 4; ++i) {
        const int tok = tokBase + tg * 4 + i;
#pragma unroll
        for (int j = 0; j < 4; ++j) {
            const int e = eg * 4 + j;
            const float z = (float)acc[i][j];
            const float a = 1.0f / (1.0f + expf(-z));
            A[(size_t)tok * NE + e] = a;
        }
    }
}

// ---------------------------------------------------------------------------
// Kernel 2: per-token top-8 (lax.top_k semantics: descending value, ties ->
// lower index), gate normalization, and accumulation of per-expert P-sums
// (normalized affinity) and selection counts.
// One wave per 16 tokens (serial); 256 threads = 4 waves; 64 tokens/block.
// ---------------------------------------------------------------------------
__global__ __launch_bounds__(256) void topk_gate(const float* __restrict__ A,
                                                 const float* __restrict__ bias,
                                                 float* __restrict__ gates,
                                                 float* __restrict__ idxf,
                                                 float* __restrict__ gP,
                                                 float* __restrict__ gC) {
    __shared__ float Pl[NE];
    __shared__ float Cl[NE];
    const int tid = threadIdx.x;
    if (tid < NE) { Pl[tid] = 0.0f; Cl[tid] = 0.0f; }
    __syncthreads();

    const int lane = tid & 63;
    const int wv   = tid >> 6;                 // 0..3
    const int tok0 = blockIdx.x * 64 + wv * 16;
    const float b  = bias[lane];

    float pacc = 0.0f;   // sum over my tokens of a_lane / rowsum
    float cacc = 0.0f;   // how many times my expert (=lane) was selected

    for (int it = 0; it < 16; ++it) {
        const int t = tok0 + it;
        const float a = A[(size_t)t * NE + lane];

        float rs = a;
#pragma unroll
        for (int off = 32; off; off >>= 1) rs += __shfl_xor(rs, off, 64);
        pacc += a / (rs + EPSV);

        float s = a + b;
        float gk[NACT];
        int   ik[NACT];
        float gsum = 0.0f;

#pragma unroll
        for (int k = 0; k < NACT; ++k) {
            float v = s;
            int  vi = lane;
#pragma unroll
            for (int off = 32; off; off >>= 1) {
                const float ov = __shfl_xor(v, off, 64);
                const int   oi = __shfl_xor(vi, off, 64);
                if (ov > v || (ov == v && oi < vi)) { v = ov; vi = oi; }
            }
            const float ga = __shfl(a, vi, 64);
            gk[k] = ga;
            ik[k] = vi;
            gsum += ga;
            if (lane == vi) { s = -INFINITY; cacc += 1.0f; }
        }

        const float inv = 1.0f / (gsum + EPSV);
        if (lane == 0) {
#pragma unroll
            for (int k = 0; k < NACT; ++k) {
                gates[(size_t)t * NACT + k] = gk[k] * inv;
                idxf [(size_t)t * NACT + k] = (float)ik[k];
            }
        }
    }

    atomicAdd(&Pl[lane], pacc);
    atomicAdd(&Cl[lane], cacc);
    __syncthreads();
    if (tid < NE) {
        atomicAdd(&gP[tid], Pl[tid]);
        atomicAdd(&gC[tid], Cl[tid]);
    }
}

// ---------------------------------------------------------------------------
// Kernel 3: balance loss = alpha * sum_e f_e * P_e
// ---------------------------------------------------------------------------
__global__ void loss_k(const float* __restrict__ gP,
                       const float* __restrict__ gC,
                       float* __restrict__ out) {
    const int e = threadIdx.x;   // 64 threads
    const float f = gC[e] * ((float)NE / (float)(NACT * T_TOK));
    const float P = gP[e] / (float)T_TOK;
    float v = f * P;
#pragma unroll
    for (int off = 32; off; off >>= 1) v += __shfl_xor(v, off, 64);
    if (e == 0) out[0] = ALPHA * v;
}

__global__ void zero_k(float* __restrict__ p, int n) {
    const int i = blockIdx.x * blockDim.x + threadIdx.x;
    if (i < n) p[i] = 0.0f;
}

extern "C" void kernel_launch(void* const* d_in, const int* in_sizes, int n_in,
                              void* d_out, int out_size, void* d_ws, size_t ws_size,
                              hipStream_t stream) {
    const float* x    = (const float*)d_in[0];
    const float* Wg   = (const float*)d_in[1];
    const float* bias = (const float*)d_in[2];
    float* out = (float*)d_out;

    float* A  = (float*)d_ws;                                    // T*64 fp32 = 4 MB
    float* gP = (float*)((char*)d_ws + (size_t)T_TOK * NE * 4);  // 64 floats
    float* gC = gP + NE;                                         // 64 floats

    zero_k<<<1, 128, 0, stream>>>(gP, 2 * NE);
    gemm_aff<<<T_TOK / 64, 256, 0, stream>>>(x, Wg, A);
    topk_gate<<<T_TOK / 64, 256, 0, stream>>>(A, bias, out,
                                              out + (size_t)T_TOK * NACT, gP, gC);
    loss_k<<<1, 64, 0, stream>>>(gP, gC, out + 2 * (size_t)T_TOK * NACT);
}

// Round 2
// 395.843 us; speedup vs baseline: 1.3498x; 1.3498x over previous
//
#include <hip/hip_runtime.h>
#include <math.h>

#define T_TOK 16384
#define DIM   2048
#define NE    64
#define NACT  8
#define ALPHA 1e-4f
#define EPSV  1e-9f
#define BK    64          // K-chunk (floats) staged per iteration
#define BT    32          // tokens per block

// LDS pitches (in doubles). 66 = 64 + 2 pad, keeps 16B alignment for double2.
#define PW 66
#define PX 66
#define PA 65             // aff[] pitch in floats

// ---------------------------------------------------------------------------
// Fused kernel: affinity = sigmoid(x @ W^T) with fp64 accumulation (index
// ordering must match an fp64 numpy reference — round-1 evidence), then
// per-token top-8 + gate normalization + balance-loss partials, all in-block.
//
// Grid: 512 blocks x 256 threads (2 blocks/CU, 8 waves/CU). Tile: 32 tok x
// 64 experts, full K in BK=64 chunks. Per-thread: 4 tokens (tm+8i) x
// 2 experts (2*ep+j) -> 8 fp64 accumulators.
//
// LDS: tiles stored as fp64 (convert at stage time, not in the 32x-reused
// inner loop). W stored dd-major with expert permutation pe=(e>>1)+32*(e&1)
// so the read pattern (e = 2*ep+j, ep=lane&31) is 2-way bank-aliased (free).
// x stored tok-major; per-read only 2 distinct rows/wave (tm=tid>>5) ->
// broadcast, conflict-free.
// ---------------------------------------------------------------------------
__global__ __launch_bounds__(256) void router_fused(
        const float* __restrict__ x,
        const float* __restrict__ Wg,
        const float* __restrict__ bias,
        float* __restrict__ gates,
        float* __restrict__ idxf,
        float* __restrict__ gP,
        float* __restrict__ gC) {
    __shared__ __align__(16) double sW[BK * PW];   // [dd][pe]
    __shared__ __align__(16) double sX[BT * PX];   // [tok][dd]
    __shared__ float Pl[NE];
    __shared__ float Cl[NE];

    const int tid = threadIdx.x;
    const int tokBase = blockIdx.x * BT;
    const int tm = tid >> 5;       // 0..7  : tokens tm, tm+8, tm+16, tm+24
    const int ep = tid & 31;       // 0..31 : experts 2*ep, 2*ep+1

    double acc[4][2];
#pragma unroll
    for (int i = 0; i < 4; ++i) { acc[i][0] = 0.0; acc[i][1] = 0.0; }

    for (int c = 0; c < DIM; c += BK) {
        // ---- stage x-tile (32 tok x 64 dd) as fp64, tok-major ----
#pragma unroll
        for (int q = 0; q < 2; ++q) {
            const int f   = tid + q * 256;       // 0..511
            const int tok = f >> 4;              // 0..31
            const int d4  = (f & 15) * 4;        // 0..60
            const float4 v = *(const float4*)(x + (size_t)(tokBase + tok) * DIM + c + d4);
            double2 lo, hi;
            lo.x = (double)v.x; lo.y = (double)v.y;
            hi.x = (double)v.z; hi.y = (double)v.w;
            *(double2*)&sX[tok * PX + d4]     = lo;
            *(double2*)&sX[tok * PX + d4 + 2] = hi;
        }
        // ---- stage W-tile (64 e x 64 dd) as fp64, dd-major, e permuted ----
#pragma unroll
        for (int q = 0; q < 4; ++q) {
            const int g  = tid + q * 256;        // 0..1023
            const int e  = g >> 4;               // 0..63
            const int d4 = (g & 15) * 4;
            const float4 v = *(const float4*)(Wg + (size_t)e * DIM + c + d4);
            const int pe = (e >> 1) + 32 * (e & 1);
            sW[(d4 + 0) * PW + pe] = (double)v.x;
            sW[(d4 + 1) * PW + pe] = (double)v.y;
            sW[(d4 + 2) * PW + pe] = (double)v.z;
            sW[(d4 + 3) * PW + pe] = (double)v.w;
        }
        __syncthreads();

        // ---- compute: 16 x (4 dd) steps ----
#pragma unroll 4
        for (int d4 = 0; d4 < BK; d4 += 4) {
            double xd[4][4];
#pragma unroll
            for (int i = 0; i < 4; ++i) {
                const double2 a = *(const double2*)&sX[(tm + 8 * i) * PX + d4];
                const double2 b = *(const double2*)&sX[(tm + 8 * i) * PX + d4 + 2];
                xd[i][0] = a.x; xd[i][1] = a.y; xd[i][2] = b.x; xd[i][3] = b.y;
            }
            double wd[2][4];
#pragma unroll
            for (int j = 0; j < 2; ++j)
#pragma unroll
                for (int jj = 0; jj < 4; ++jj)
                    wd[j][jj] = sW[(d4 + jj) * PW + ep + 32 * j];
#pragma unroll
            for (int i = 0; i < 4; ++i)
#pragma unroll
                for (int j = 0; j < 2; ++j)
#pragma unroll
                    for (int jj = 0; jj < 4; ++jj)
                        acc[i][j] = fma(xd[i][jj], wd[j][jj], acc[i][j]);
        }
        __syncthreads();
    }

    // ---- epilogue: affinity -> LDS (aliases sX region), then top-8 ----
    float* aff = (float*)sX;   // BT x PA floats = 8320 B < 16896 B
    __syncthreads();           // ensure all compute reads of sX are done
#pragma unroll
    for (int i = 0; i < 4; ++i) {
        const int t = tm + 8 * i;
#pragma unroll
        for (int j = 0; j < 2; ++j) {
            const float z = (float)acc[i][j];
            aff[t * PA + 2 * ep + j] = 1.0f / (1.0f + expf(-z));
        }
    }
    if (tid < NE) { Pl[tid] = 0.0f; Cl[tid] = 0.0f; }
    __syncthreads();

    const int lane = tid & 63;
    const int wv   = tid >> 6;            // 0..3, each wave: 8 tokens
    const float b  = bias[lane];

    float pacc = 0.0f;
    float cacc = 0.0f;

    for (int it = 0; it < 8; ++it) {
        const int t = wv * 8 + it;        // local token
        const float a = aff[t * PA + lane];

        float rs = a;
#pragma unroll
        for (int off = 32; off; off >>= 1) rs += __shfl_xor(rs, off, 64);
        pacc += a / (rs + EPSV);

        float s = a + b;
        float gk[NACT];
        int   ik[NACT];
        float gsum = 0.0f;

#pragma unroll
        for (int k = 0; k < NACT; ++k) {
            float v = s;
            int  vi = lane;
#pragma unroll
            for (int off = 32; off; off >>= 1) {
                const float ov = __shfl_xor(v, off, 64);
                const int   oi = __shfl_xor(vi, off, 64);
                if (ov > v || (ov == v && oi < vi)) { v = ov; vi = oi; }
            }
            const float ga = __shfl(a, vi, 64);
            gk[k] = ga;
            ik[k] = vi;
            gsum += ga;
            if (lane == vi) { s = -INFINITY; cacc += 1.0f; }
        }

        const float inv = 1.0f / (gsum + EPSV);
        if (lane == 0) {
            const int gt = tokBase + t;
#pragma unroll
            for (int k = 0; k < NACT; ++k) {
                gates[(size_t)gt * NACT + k] = gk[k] * inv;
                idxf [(size_t)gt * NACT + k] = (float)ik[k];
            }
        }
    }

    atomicAdd(&Pl[lane], pacc);
    atomicAdd(&Cl[lane], cacc);
    __syncthreads();
    if (tid < NE) {
        atomicAdd(&gP[tid], Pl[tid]);
        atomicAdd(&gC[tid], Cl[tid]);
    }
}

// ---------------------------------------------------------------------------
__global__ void loss_k(const float* __restrict__ gP,
                       const float* __restrict__ gC,
                       float* __restrict__ out) {
    const int e = threadIdx.x;   // 64 threads
    const float f = gC[e] * ((float)NE / (float)(NACT * T_TOK));
    const float P = gP[e] / (float)T_TOK;
    float v = f * P;
#pragma unroll
    for (int off = 32; off; off >>= 1) v += __shfl_xor(v, off, 64);
    if (e == 0) out[0] = ALPHA * v;
}

__global__ void zero_k(float* __restrict__ p, int n) {
    const int i = blockIdx.x * blockDim.x + threadIdx.x;
    if (i < n) p[i] = 0.0f;
}

extern "C" void kernel_launch(void* const* d_in, const int* in_sizes, int n_in,
                              void* d_out, int out_size, void* d_ws, size_t ws_size,
                              hipStream_t stream) {
    const float* x    = (const float*)d_in[0];
    const float* Wg   = (const float*)d_in[1];
    const float* bias = (const float*)d_in[2];
    float* out = (float*)d_out;

    float* gP = (float*)d_ws;       // 64 floats
    float* gC = gP + NE;            // 64 floats

    zero_k<<<1, 128, 0, stream>>>(gP, 2 * NE);
    router_fused<<<T_TOK / BT, 256, 0, stream>>>(
        x, Wg, bias, out, out + (size_t)T_TOK * NACT, gP, gC);
    loss_k<<<1, 64, 0, stream>>>(gP, gC, out + 2 * (size_t)T_TOK * NACT);
}